// Round 1
// baseline (940.687 us; speedup 1.0000x reference)
//
#include <hip/hip_runtime.h>
#include <stdint.h>

typedef int v4i __attribute__((ext_vector_type(4)));

#define MDIM 16384   // B*S = 4*4096
#define NDIM 8192    // D_OUT
#define KDIM 2048    // D_IN

// ---------------------------------------------------------------------------
// Kernel 1: partial sums of |w| in double (deterministic tree reduction).
// 2048 blocks x 256 threads; 16777216 floats = 4194304 float4; 8 float4/thread.
// ---------------------------------------------------------------------------
__global__ __launch_bounds__(256) void absw_partial_kernel(
    const float* __restrict__ w, double* __restrict__ part) {
  const float4* wv = (const float4*)w;
  const int t = threadIdx.x;
  const int tid = blockIdx.x * 256 + t;
  double s = 0.0;
#pragma unroll
  for (int i = 0; i < 8; ++i) {
    float4 v = wv[tid + i * (2048 * 256)];
    s += (double)fabsf(v.x) + (double)fabsf(v.y) +
         (double)fabsf(v.z) + (double)fabsf(v.w);
  }
  __shared__ double red[256];
  red[t] = s;
  __syncthreads();
  for (int off = 128; off > 0; off >>= 1) {
    if (t < off) red[t] += red[t + off];
    __syncthreads();
  }
  if (t == 0) part[blockIdx.x] = red[0];
}

// ---------------------------------------------------------------------------
// Kernel 2: reduce 2048 partials -> fp32 weight scale = clip(mean|w|, 1e-8).
// ---------------------------------------------------------------------------
__global__ __launch_bounds__(256) void absw_finalize_kernel(
    const double* __restrict__ part, float* __restrict__ wscale) {
  const int t = threadIdx.x;
  double s = 0.0;
#pragma unroll
  for (int i = 0; i < 8; ++i) s += part[t + i * 256];
  __shared__ double red[256];
  red[t] = s;
  __syncthreads();
  for (int off = 128; off > 0; off >>= 1) {
    if (t < off) red[t] += red[t + off];
    __syncthreads();
  }
  if (t == 0) {
    double mean = red[0] / 16777216.0;
    float sc = (float)mean;
    if (sc < 1e-8f) sc = 1e-8f;
    wscale[0] = sc;
  }
}

// ---------------------------------------------------------------------------
// Kernel 3: ternarize weights: q = clip(rint(w/scale), -1, 1) as int8.
// 16384 blocks x 256 threads, one float4 -> 4 packed bytes each.
// ---------------------------------------------------------------------------
__global__ __launch_bounds__(256) void quant_w_kernel(
    const float* __restrict__ w, const float* __restrict__ wscale,
    uint32_t* __restrict__ qw) {
  const int idx = blockIdx.x * 256 + threadIdx.x;  // 0..4194303
  const float s = wscale[0];
  float4 v = ((const float4*)w)[idx];
  int q0 = (int)fminf(fmaxf(rintf(v.x / s), -1.f), 1.f);
  int q1 = (int)fminf(fmaxf(rintf(v.y / s), -1.f), 1.f);
  int q2 = (int)fminf(fmaxf(rintf(v.z / s), -1.f), 1.f);
  int q3 = (int)fminf(fmaxf(rintf(v.w / s), -1.f), 1.f);
  uint32_t p = (uint32_t)(uint8_t)(int8_t)q0 |
               ((uint32_t)(uint8_t)(int8_t)q1 << 8) |
               ((uint32_t)(uint8_t)(int8_t)q2 << 16) |
               ((uint32_t)(uint8_t)(int8_t)q3 << 24);
  qw[idx] = p;
}

// ---------------------------------------------------------------------------
// Kernel 4: RMSNorm + activation quant. One block (256 thr) per row of 2048.
// Each thread owns 8 consecutive elements (two float4 loads).
// ---------------------------------------------------------------------------
__global__ __launch_bounds__(256) void rms_quant_x_kernel(
    const float* __restrict__ x, const float* __restrict__ gamma,
    uint64_t* __restrict__ qa, float* __restrict__ rowscale) {
  const int row = blockIdx.x;
  const int t = threadIdx.x;
  const float4* xr = (const float4*)(x + (size_t)row * KDIM);
  float4 v0 = xr[t * 2];
  float4 v1 = xr[t * 2 + 1];
  float xs[8] = {v0.x, v0.y, v0.z, v0.w, v1.x, v1.y, v1.z, v1.w};
  float ss = 0.f;
#pragma unroll
  for (int i = 0; i < 8; ++i) ss += xs[i] * xs[i];

  __shared__ float red[256];
  red[t] = ss;
  __syncthreads();
  for (int off = 128; off > 0; off >>= 1) {
    if (t < off) red[t] += red[t + off];
    __syncthreads();
  }
  const float rstd = rsqrtf(red[0] / 2048.0f + 1e-6f);

  const float4* gr = (const float4*)gamma;
  float4 g0 = gr[t * 2];
  float4 g1 = gr[t * 2 + 1];
  float gs[8] = {g0.x, g0.y, g0.z, g0.w, g1.x, g1.y, g1.z, g1.w};
  float xn[8];
  float am = 0.f;
#pragma unroll
  for (int i = 0; i < 8; ++i) {
    xn[i] = xs[i] * rstd * gs[i];
    am = fmaxf(am, fabsf(xn[i]));
  }
  __syncthreads();  // done reading red[0] from sum phase
  red[t] = am;
  __syncthreads();
  for (int off = 128; off > 0; off >>= 1) {
    if (t < off) red[t] = fmaxf(red[t], red[t + off]);
    __syncthreads();
  }
  const float amax = fmaxf(red[0], 1e-5f);
  const float scale = 127.0f / amax;

  uint64_t p = 0;
#pragma unroll
  for (int i = 0; i < 8; ++i) {
    int q = (int)fminf(fmaxf(rintf(xn[i] * scale), -128.f), 127.f);
    p |= (uint64_t)(uint8_t)(int8_t)q << (8 * i);
  }
  qa[(size_t)row * 256 + t] = p;
  if (t == 0) rowscale[row] = 1.0f / scale;
}

// ---------------------------------------------------------------------------
// Kernel 5: int8 x ternary GEMM. C[m][n] = rowfac[m] * sum_k qa[m][k]*qw[n][k]
// 128x128 tile, BK=64, 4 waves (2x2), 16x16x64 i8 MFMA, global_load_lds
// width-16 staging with XOR chunk swizzle (pc = c ^ ((row>>1)&3)).
// ---------------------------------------------------------------------------
__global__ __launch_bounds__(256) void gemm_i8_kernel(
    const int8_t* __restrict__ qa, const int8_t* __restrict__ qw,
    const float* __restrict__ rowscale, float* __restrict__ out) {
  __shared__ char smA[128 * 64];  // 8 KB
  __shared__ char smB[128 * 64];  // 8 KB

  const int tid = threadIdx.x;
  const int w = tid >> 6;
  const int l = tid & 63;
  const int bm = blockIdx.y;
  const int bn = blockIdx.x;
  const int wm = w >> 1;
  const int wn = w & 1;

  // staging: lane l loads row (group*16 + l>>2), source chunk c=(l&3)^((l>>3)&3)
  const int rA = l >> 2;
  const int ck = ((l & 3) ^ ((l >> 3) & 3)) << 4;

  const int8_t* gA0 = qa + (size_t)(bm * 128 + w * 16 + rA) * KDIM + ck;
  const int8_t* gA1 = qa + (size_t)(bm * 128 + (4 + w) * 16 + rA) * KDIM + ck;
  const int8_t* gB0 = qw + (size_t)(bn * 128 + w * 16 + rA) * KDIM + ck;
  const int8_t* gB1 = qw + (size_t)(bn * 128 + (4 + w) * 16 + rA) * KDIM + ck;

  char* ldsA0 = smA + w * 1024;        // wave-uniform bases
  char* ldsA1 = smA + (4 + w) * 1024;
  char* ldsB0 = smB + w * 1024;
  char* ldsB1 = smB + (4 + w) * 1024;

  v4i acc[4][4];
  const v4i vzero = {0, 0, 0, 0};
#pragma unroll
  for (int i = 0; i < 4; ++i)
#pragma unroll
    for (int j = 0; j < 4; ++j) acc[i][j] = vzero;

  // fragment LDS byte offsets (swizzle-corrected)
  const int kc = l >> 4;
  int offA[4], offB[4];
#pragma unroll
  for (int i = 0; i < 4; ++i) {
    int rm = wm * 64 + i * 16 + (l & 15);
    offA[i] = rm * 64 + ((kc ^ ((rm >> 1) & 3)) << 4);
    int rn = wn * 64 + i * 16 + (l & 15);
    offB[i] = rn * 64 + ((kc ^ ((rn >> 1) & 3)) << 4);
  }

  for (int ko = 0; ko < KDIM; ko += 64) {
    __builtin_amdgcn_global_load_lds(
        (const __attribute__((address_space(1))) void*)(gA0 + ko),
        (__attribute__((address_space(3))) void*)ldsA0, 16, 0, 0);
    __builtin_amdgcn_global_load_lds(
        (const __attribute__((address_space(1))) void*)(gA1 + ko),
        (__attribute__((address_space(3))) void*)ldsA1, 16, 0, 0);
    __builtin_amdgcn_global_load_lds(
        (const __attribute__((address_space(1))) void*)(gB0 + ko),
        (__attribute__((address_space(3))) void*)ldsB0, 16, 0, 0);
    __builtin_amdgcn_global_load_lds(
        (const __attribute__((address_space(1))) void*)(gB1 + ko),
        (__attribute__((address_space(3))) void*)ldsB1, 16, 0, 0);
    __syncthreads();

    v4i af[4], bf[4];
#pragma unroll
    for (int i = 0; i < 4; ++i) {
      af[i] = *(const v4i*)(smA + offA[i]);
      bf[i] = *(const v4i*)(smB + offB[i]);
    }
#pragma unroll
    for (int i = 0; i < 4; ++i)
#pragma unroll
      for (int j = 0; j < 4; ++j)
        acc[i][j] = __builtin_amdgcn_mfma_i32_16x16x64_i8(af[i], bf[j],
                                                          acc[i][j], 0, 0, 0);
    __syncthreads();
  }

  // epilogue: C/D layout col = l&15, row = (l>>4)*4 + reg
#pragma unroll
  for (int i = 0; i < 4; ++i) {
    const int gm0 = bm * 128 + wm * 64 + i * 16 + (l >> 4) * 4;
    const int gn0 = bn * 128 + wn * 64 + (l & 15);
#pragma unroll
    for (int r = 0; r < 4; ++r) {
      const float s = rowscale[gm0 + r];
      float* orow = out + (size_t)(gm0 + r) * NDIM + gn0;
#pragma unroll
      for (int j = 0; j < 4; ++j) orow[j * 16] = s * (float)acc[i][j][r];
    }
  }
}

// ---------------------------------------------------------------------------
extern "C" void kernel_launch(void* const* d_in, const int* in_sizes, int n_in,
                              void* d_out, int out_size, void* d_ws,
                              size_t ws_size, hipStream_t stream) {
  const float* x = (const float*)d_in[0];       // 16384*2048
  const float* weight = (const float*)d_in[1];  // 8192*2048
  const float* gamma = (const float*)d_in[2];   // 2048
  float* out = (float*)d_out;                   // 16384*8192

  char* ws = (char*)d_ws;
  int8_t* qw = (int8_t*)ws;                          // 16777216 B
  int8_t* qa = (int8_t*)(ws + 16777216);             // 33554432 B
  float* rowfac = (float*)(ws + 50331648);           // 65536 B
  double* part = (double*)(ws + 50397184);           // 16384 B
  float* wscale = (float*)(ws + 50397184 + 16384);   // 4 B

  absw_partial_kernel<<<2048, 256, 0, stream>>>(weight, part);
  absw_finalize_kernel<<<1, 256, 0, stream>>>(part, wscale);
  quant_w_kernel<<<16384, 256, 0, stream>>>(weight, wscale, (uint32_t*)qw);
  rms_quant_x_kernel<<<16384, 256, 0, stream>>>(x, gamma, (uint64_t*)qa,
                                                rowfac);
  gemm_i8_kernel<<<dim3(64, 128), 256, 0, stream>>>(qa, qw, rowfac, out);
}